// Round 1
// baseline (852004.688 us; speedup 1.0000x reference)
//
#include <hip/hip_runtime.h>
#include <math.h>

// ---------------------------------------------------------------------------
// GameProcessor: sequential scan over 30000 games updating a 364x512 embedding
// table with a GRU-ish cell + layernorm, emitting per-game contexts (proj).
//
// Design (round 1):
//  * Dependency-parallel execution: game g depends only on the previous games
//    that touched team_a[g] / team_b[g]. deps precomputed on-device; a
//    persistent kernel (256 blocks x 512 thr) spin-waits on per-game done[]
//    flags with agent-scope acquire/release atomics. Deadlock-free: deps point
//    to strictly smaller game ids and each block walks its games in order.
//  * All weight matrices pre-transposed into d_ws so inner-loop weight loads
//    are lane-coalesced (avoid L1 thrash of per-lane row streaming).
//  * fp32 throughout (correctness anchor; bf16 weights are a later lever).
//  * emb state lives in d_out's final_emb region (init by d2d copy each call).
// ---------------------------------------------------------------------------

#define NG   30000
#define NT   364
#define ND   512
#define NF   28
#define NH   128
#define NCIN 1053   // 2*ND + NF + 1

static constexpr int NBLOCKS = 256;
static constexpr int BLK     = 512;

__global__ void zero_kernel(int* p, int n) {
  int i = blockIdx.x * blockDim.x + threadIdx.x;
  if (i < n) p[i] = 0;
}

// dep0[g]/dep1[g] = most recent earlier game touching team_a[g]/team_b[g], or -1.
__global__ void deps_kernel(const int* __restrict__ ta, const int* __restrict__ tb,
                            int* __restrict__ dep0, int* __restrict__ dep1) {
  int g = blockIdx.x * blockDim.x + threadIdx.x;
  if (g >= NG) return;
  int a = ta[g], b = tb[g];
  int d0 = -1, d1 = -1;
  for (int p = g - 1; p >= 0; --p) {
    int pa = ta[p], pb = tb[p];
    if (d0 < 0 && (pa == a || pb == a)) d0 = p;
    if (d1 < 0 && (pa == b || pb == b)) d1 = p;
    if (d0 >= 0 && d1 >= 0) break;
  }
  dep0[g] = d0;
  dep1[g] = d1;
}

// dst[k*R + j] = src[j*C + k]  (src is R x C row-major; dst is C x R)
__global__ void transpose_kernel(const float* __restrict__ src, float* __restrict__ dst,
                                 int R, int C) {
  long long idx = (long long)blockIdx.x * blockDim.x + threadIdx.x;
  long long total = (long long)R * C;
  if (idx >= total) return;
  int j = (int)(idx % R);
  int k = (int)(idx / R);
  dst[idx] = src[(long long)j * C + k];
}

__device__ __forceinline__ float sigmf(float x) { return 1.0f / (1.0f + expf(-x)); }

template <bool TR>
__global__ __launch_bounds__(BLK, 2)
void game_kernel(const float* __restrict__ Wp,   const float* __restrict__ bp,
                 const float* __restrict__ W_ih, const float* __restrict__ b_ih,
                 const float* __restrict__ W_hh, const float* __restrict__ b_hh,
                 const float* __restrict__ ln_g, const float* __restrict__ ln_b,
                 const float* __restrict__ Wi1,  const float* __restrict__ bi1,
                 const float* __restrict__ Wi2,  const float* __restrict__ bi2,
                 const float* __restrict__ fA,   const float* __restrict__ fB,
                 const int* __restrict__ team_a, const int* __restrict__ team_b,
                 const int* __restrict__ a_won,
                 float* __restrict__ emb,   // T*D region of d_out (working state)
                 float* __restrict__ ctx,   // G*2*D region of d_out
                 const int* __restrict__ dep0, const int* __restrict__ dep1,
                 int* __restrict__ done,
                 const float* __restrict__ WpT, const float* __restrict__ Wi1T,
                 const float* __restrict__ WihT, const float* __restrict__ WhhT) {
  const int tid = threadIdx.x;

  __shared__ float sA[ND], sB[ND];     // current emb rows (e_self[0], e_self[1])
  __shared__ float sP0[ND], sP1[ND];   // proj rows
  __shared__ float sFa[NF], sFb[NF];
  __shared__ float sH[2 * NH];
  __shared__ float sImp[2];
  __shared__ float sRed[4][8];
  __shared__ float sStat[4];           // mu0, rstd0, mu1, rstd1

  for (int g = blockIdx.x; g < NG; g += gridDim.x) {
    // ---- wait for dependencies (thread 0 spins; acquire invalidates caches)
    if (tid == 0) {
      int d0 = dep0[g], d1 = dep1[g];
      if (d0 >= 0)
        while (__hip_atomic_load(done + d0, __ATOMIC_ACQUIRE, __HIP_MEMORY_SCOPE_AGENT) == 0)
          __builtin_amdgcn_s_sleep(1);
      if (d1 >= 0)
        while (__hip_atomic_load(done + d1, __ATOMIC_ACQUIRE, __HIP_MEMORY_SCOPE_AGENT) == 0)
          __builtin_amdgcn_s_sleep(1);
    }
    __syncthreads();

    const int ta = team_a[g], tb = team_b[g];
    const float aw = (float)a_won[g];

    // ---- stage state + features
    sA[tid] = emb[(size_t)ta * ND + tid];
    sB[tid] = emb[(size_t)tb * ND + tid];
    if (tid < NF) {
      sFa[tid] = fA[(size_t)g * NF + tid];
      sFb[tid] = fB[(size_t)g * NF + tid];
    }
    __syncthreads();

    // ---- phase A: proj = relu(comb @ Wp^T + bp); comb0=[eA|eB|fa|aw], comb1=[eB|eA|fb|1-aw]
    float acc0 = bp[tid], acc1 = acc0;
#pragma unroll 4
    for (int k = 0; k < ND; ++k) {
      float w1 = TR ? WpT[(size_t)k * ND + tid]        : Wp[(size_t)tid * NCIN + k];
      float w2 = TR ? WpT[(size_t)(ND + k) * ND + tid] : Wp[(size_t)tid * NCIN + ND + k];
      float a = sA[k], b = sB[k];
      acc0 = fmaf(a, w1, acc0); acc0 = fmaf(b, w2, acc0);
      acc1 = fmaf(b, w1, acc1); acc1 = fmaf(a, w2, acc1);
    }
#pragma unroll
    for (int f = 0; f < NF; ++f) {
      float wf = TR ? WpT[(size_t)(2 * ND + f) * ND + tid] : Wp[(size_t)tid * NCIN + 2 * ND + f];
      acc0 = fmaf(sFa[f], wf, acc0);
      acc1 = fmaf(sFb[f], wf, acc1);
    }
    {
      float wl = TR ? WpT[(size_t)(NCIN - 1) * ND + tid] : Wp[(size_t)tid * NCIN + (NCIN - 1)];
      acc0 = fmaf(aw, wl, acc0);
      acc1 = fmaf(1.0f - aw, wl, acc1);
    }
    float p0 = fmaxf(acc0, 0.0f), p1 = fmaxf(acc1, 0.0f);
    sP0[tid] = p0; sP1[tid] = p1;
    ctx[(size_t)g * (2 * ND) + tid]      = p0;   // contexts[g,0,:]
    ctx[(size_t)g * (2 * ND) + ND + tid] = p1;   // contexts[g,1,:]
    __syncthreads();

    // ---- phase B: imp = sigmoid(relu(proj @ Wi1^T + bi1) @ Wi2^T + bi2)
    if (tid < 2 * NH) {
      const int r = tid >> 7, h = tid & (NH - 1);
      const float* pr = r ? sP1 : sP0;
      float acc = bi1[h];
      for (int k = 0; k < ND; ++k) {
        float w = TR ? Wi1T[(size_t)k * NH + h] : Wi1[(size_t)h * ND + k];
        acc = fmaf(pr[k], w, acc);
      }
      sH[tid] = fmaxf(acc, 0.0f);
    }
    __syncthreads();
    if (tid < 2) {
      float acc = bi2[0];
      for (int h = 0; h < NH; ++h) acc = fmaf(sH[tid * NH + h], Wi2[h], acc);
      sImp[tid] = sigmf(acc);
    }
    __syncthreads();

    // ---- phase C: gi = proj @ W_ih^T + b_ih ; gh = e_self @ W_hh^T + b_hh
    float ir0 = b_ih[tid],           ir1 = ir0;
    float iz0 = b_ih[ND + tid],      iz1 = iz0;
    float in0 = b_ih[2 * ND + tid],  in1 = in0;
    float hr0 = b_hh[tid],           hr1 = hr0;
    float hz0 = b_hh[ND + tid],      hz1 = hz0;
    float hn0 = b_hh[2 * ND + tid],  hn1 = hn0;
#pragma unroll 4
    for (int k = 0; k < ND; ++k) {
      float q0 = sP0[k], q1 = sP1[k], a = sA[k], b = sB[k];
      float wr = TR ? WihT[(size_t)k * (3 * ND) + tid]
                    : W_ih[(size_t)tid * ND + k];
      float wz = TR ? WihT[(size_t)k * (3 * ND) + ND + tid]
                    : W_ih[(size_t)(ND + tid) * ND + k];
      float wn = TR ? WihT[(size_t)k * (3 * ND) + 2 * ND + tid]
                    : W_ih[(size_t)(2 * ND + tid) * ND + k];
      ir0 = fmaf(q0, wr, ir0); ir1 = fmaf(q1, wr, ir1);
      iz0 = fmaf(q0, wz, iz0); iz1 = fmaf(q1, wz, iz1);
      in0 = fmaf(q0, wn, in0); in1 = fmaf(q1, wn, in1);
      float vr = TR ? WhhT[(size_t)k * (3 * ND) + tid]
                    : W_hh[(size_t)tid * ND + k];
      float vz = TR ? WhhT[(size_t)k * (3 * ND) + ND + tid]
                    : W_hh[(size_t)(ND + tid) * ND + k];
      float vn = TR ? WhhT[(size_t)k * (3 * ND) + 2 * ND + tid]
                    : W_hh[(size_t)(2 * ND + tid) * ND + k];
      hr0 = fmaf(a, vr, hr0); hr1 = fmaf(b, vr, hr1);
      hz0 = fmaf(a, vz, hz0); hz1 = fmaf(b, vz, hz1);
      hn0 = fmaf(a, vn, hn0); hn1 = fmaf(b, vn, hn1);
    }

    // ---- phase D: GRU cell + imp blend + layernorm + state write
    float e0 = sA[tid], e1 = sB[tid];
    float r0 = sigmf(ir0 + hr0), r1 = sigmf(ir1 + hr1);
    float z0 = sigmf(iz0 + hz0), z1 = sigmf(iz1 + hz1);
    float n0 = tanhf(in0 + r0 * hn0), n1 = tanhf(in1 + r1 * hn1);
    float nh0 = (1.0f - z0) * n0 + z0 * e0;
    float nh1 = (1.0f - z1) * n1 + z1 * e1;
    float im0 = sImp[0], im1 = sImp[1];
    float u0 = e0 + im0 * (nh0 - e0);
    float u1 = e1 + im1 * (nh1 - e1);

    float s0 = u0, q0 = u0 * u0, s1 = u1, q1 = u1 * u1;
#pragma unroll
    for (int off = 32; off > 0; off >>= 1) {
      s0 += __shfl_xor(s0, off); q0 += __shfl_xor(q0, off);
      s1 += __shfl_xor(s1, off); q1 += __shfl_xor(q1, off);
    }
    const int lane = tid & 63, wv = tid >> 6;
    if (lane == 0) { sRed[0][wv] = s0; sRed[1][wv] = q0; sRed[2][wv] = s1; sRed[3][wv] = q1; }
    __syncthreads();
    if (tid == 0) {
      float S0 = 0, Q0 = 0, S1 = 0, Q1 = 0;
#pragma unroll
      for (int w = 0; w < 8; ++w) { S0 += sRed[0][w]; Q0 += sRed[1][w]; S1 += sRed[2][w]; Q1 += sRed[3][w]; }
      float mu0 = S0 * (1.0f / ND), mu1 = S1 * (1.0f / ND);
      float v0 = Q0 * (1.0f / ND) - mu0 * mu0;
      float v1 = Q1 * (1.0f / ND) - mu1 * mu1;
      sStat[0] = mu0; sStat[1] = 1.0f / sqrtf(v0 + 1e-5f);
      sStat[2] = mu1; sStat[3] = 1.0f / sqrtf(v1 + 1e-5f);
    }
    __syncthreads();
    float gg = ln_g[tid], bb = ln_b[tid];
    float o0 = (u0 - sStat[0]) * sStat[1] * gg + bb;
    float o1 = (u1 - sStat[2]) * sStat[3] * gg + bb;
    // emb.at[ta].set(upd0).at[tb].set(upd1): tb wins if ta == tb
    if (ta != tb) emb[(size_t)ta * ND + tid] = o0;
    emb[(size_t)tb * ND + tid] = o1;
    __syncthreads();  // drains vmem (stores in L2) before the release flag
    if (tid == 0)
      __hip_atomic_store(done + g, 1, __ATOMIC_RELEASE, __HIP_MEMORY_SCOPE_AGENT);
  }
}

extern "C" void kernel_launch(void* const* d_in, const int* in_sizes, int n_in,
                              void* d_out, int out_size, void* d_ws, size_t ws_size,
                              hipStream_t stream) {
  const float* emb_table = (const float*)d_in[0];
  const float* Wp    = (const float*)d_in[1];
  const float* bp    = (const float*)d_in[2];
  const float* W_ih  = (const float*)d_in[3];
  const float* b_ih  = (const float*)d_in[4];
  const float* W_hh  = (const float*)d_in[5];
  const float* b_hh  = (const float*)d_in[6];
  const float* ln_g  = (const float*)d_in[7];
  const float* ln_b  = (const float*)d_in[8];
  const float* Wi1   = (const float*)d_in[9];
  const float* bi1   = (const float*)d_in[10];
  const float* Wi2   = (const float*)d_in[11];
  const float* bi2   = (const float*)d_in[12];
  const float* fA    = (const float*)d_in[13];
  const float* fB    = (const float*)d_in[14];
  const int*   team_a = (const int*)d_in[15];
  const int*   team_b = (const int*)d_in[16];
  const int*   a_won  = (const int*)d_in[17];

  float* out = (float*)d_out;
  float* emb = out;                       // final_emb region, used as live state
  float* ctx = out + (size_t)NT * ND;     // contexts region

  // workspace layout: [dep0|dep1|done][WpT|Wi1T|WihT|WhhT]
  char* ws = (char*)d_ws;
  int* dep0 = (int*)ws;
  int* dep1 = dep0 + NG;
  int* done = dep1 + NG;
  size_t schedBytes = (((size_t)3 * NG * sizeof(int)) + 255) & ~(size_t)255;
  float* WpT  = (float*)(ws + schedBytes);
  float* Wi1T = WpT + (size_t)NCIN * ND;
  float* WihT = Wi1T + (size_t)ND * NH;
  float* WhhT = WihT + (size_t)ND * 3 * ND;
  size_t needBytes = schedBytes +
      ((size_t)NCIN * ND + (size_t)ND * NH + 2 * (size_t)ND * 3 * ND) * sizeof(float);
  const bool tr = ws_size >= needBytes;

  // init state + schedule (every call: deterministic, graph-capture safe)
  hipMemcpyAsync(emb, emb_table, (size_t)NT * ND * sizeof(float),
                 hipMemcpyDeviceToDevice, stream);
  zero_kernel<<<(NG + 255) / 256, 256, 0, stream>>>(done, NG);
  deps_kernel<<<(NG + 255) / 256, 256, 0, stream>>>(team_a, team_b, dep0, dep1);

  if (tr) {
    transpose_kernel<<<((ND * NCIN) + 255) / 256, 256, 0, stream>>>(Wp,   WpT,  ND, NCIN);
    transpose_kernel<<<((NH * ND) + 255) / 256, 256, 0, stream>>>(Wi1,  Wi1T, NH, ND);
    transpose_kernel<<<((3 * ND * ND) + 255) / 256, 256, 0, stream>>>(W_ih, WihT, 3 * ND, ND);
    transpose_kernel<<<((3 * ND * ND) + 255) / 256, 256, 0, stream>>>(W_hh, WhhT, 3 * ND, ND);
    game_kernel<true><<<NBLOCKS, BLK, 0, stream>>>(
        Wp, bp, W_ih, b_ih, W_hh, b_hh, ln_g, ln_b, Wi1, bi1, Wi2, bi2,
        fA, fB, team_a, team_b, a_won, emb, ctx, dep0, dep1, done,
        WpT, Wi1T, WihT, WhhT);
  } else {
    game_kernel<false><<<NBLOCKS, BLK, 0, stream>>>(
        Wp, bp, W_ih, b_ih, W_hh, b_hh, ln_g, ln_b, Wi1, bi1, Wi2, bi2,
        fA, fB, team_a, team_b, a_won, emb, ctx, dep0, dep1, done,
        WpT, Wi1T, WihT, WhhT);
  }
}

// Round 2
// 67941.144 us; speedup vs baseline: 12.5403x; 12.5403x over previous
//
#include <hip/hip_runtime.h>
#include <math.h>

// ---------------------------------------------------------------------------
// GameProcessor round 2: level-synchronous, weight-stationary dataflow.
//
//  * deps: dep0/dep1 = last earlier game touching each team.
//  * levels: level[g] = 1 + max(level[deps]) computed by chunked relaxation
//    (single block). Games within a level never share a team -> parallel.
//  * counting-sort games by level -> levelStart[], levelList[].
//  * main kernel: 256 blocks, block b owns output dims {2b,2b+1}. Weight
//    slices (Wp rows, W_ih/W_hh gate rows, Wi1 row) live in LDS for the
//    whole kernel (~35 KB) -> no per-game weight streaming.
//  * per level chunk: phase A (proj -> ctx) | bar | phase C (gates -> new_h)
//    + B1 (hidden) | bar | phase D (imp, blend, layernorm, emb write) | bar.
//  * grid barrier: monotonic counter, ACQ_REL arrival + ACQUIRE spin, agent
//    scope (round-1 validated cross-XCD release/acquire on this HW).
//  * cross-block small scatters use agent-scope atomic stores (avoid
//    cross-XCD partial-line dirty write hazards).
// ---------------------------------------------------------------------------

#define NG   30000
#define NT   364
#define ND   512
#define NF   28
#define NH   128
#define NCIN 1053
#define NB   256
#define BLK  512

__device__ __forceinline__ float sigmf(float x) { return 1.0f / (1.0f + expf(-x)); }

__global__ void zero_kernel(int* p, int n) {
  int i = blockIdx.x * blockDim.x + threadIdx.x;
  if (i < n) p[i] = 0;
}

// dep0[g]/dep1[g] = most recent earlier game touching team_a[g]/team_b[g], or -1.
__global__ void deps_kernel(const int* __restrict__ ta, const int* __restrict__ tb,
                            int* __restrict__ dep0, int* __restrict__ dep1) {
  int g = blockIdx.x * blockDim.x + threadIdx.x;
  if (g >= NG) return;
  int a = ta[g], b = tb[g];
  int d0 = -1, d1 = -1;
  for (int p = g - 1; p >= 0; --p) {
    int pa = ta[p], pb = tb[p];
    if (d0 < 0 && (pa == a || pb == a)) d0 = p;
    if (d1 < 0 && (pa == b || pb == b)) d1 = p;
    if (d0 >= 0 && d1 >= 0) break;
  }
  dep0[g] = d0;
  dep1[g] = d1;
}

// Exact DAG levels via chunked monotone relaxation. Single block, 1024 thr.
__global__ void levels_kernel(const int* __restrict__ d0a, const int* __restrict__ d1a,
                              int* __restrict__ level, int* __restrict__ nLevels) {
  __shared__ int lv[1024];
  __shared__ int changed;
  __shared__ int smax;
  const int tid = threadIdx.x;
  int localMax = 0;
  if (tid == 0) smax = 0;
  for (int base = 0; base < NG; base += 1024) {
    const int g = base + tid;
    const bool val = g < NG;
    int ic0 = -1, ic1 = -1, b = 0;
    if (val) {
      int d0 = d0a[g], d1 = d1a[g];
      if (d0 >= 0) { if (d0 < base) b = max(b, level[d0] + 1); else ic0 = d0 - base; }
      if (d1 >= 0) { if (d1 < base) b = max(b, level[d1] + 1); else ic1 = d1 - base; }
    }
    lv[tid] = b;
    __syncthreads();
    for (;;) {
      if (tid == 0) changed = 0;
      __syncthreads();
      int nl = lv[tid];
      if (ic0 >= 0) nl = max(nl, lv[ic0] + 1);
      if (ic1 >= 0) nl = max(nl, lv[ic1] + 1);
      if (val && nl != lv[tid]) { lv[tid] = nl; changed = 1; }
      __syncthreads();
      if (!changed) break;
    }
    if (val) { level[g] = lv[tid]; localMax = max(localMax, lv[tid]); }
    __syncthreads();   // lv reuse + make level[] visible to next chunk reads
  }
  atomicMax(&smax, localMax);
  __syncthreads();
  if (tid == 0) nLevels[0] = smax + 1;
}

// Counting sort by level. Single block, 1024 threads.
__global__ void sort_kernel(const int* __restrict__ level, const int* __restrict__ nLevels,
                            int* __restrict__ hist, int* __restrict__ cursor,
                            int* __restrict__ levelStart, int* __restrict__ levelList) {
  const int tid = threadIdx.x;
  const int nL = nLevels[0];
  for (int i = tid; i < NG; i += 1024) { hist[i] = 0; cursor[i] = 0; }
  __syncthreads();
  for (int g = tid; g < NG; g += 1024) atomicAdd(&hist[level[g]], 1);
  __syncthreads();
  if (tid == 0) {
    int acc = 0;
    for (int i = 0; i < nL; ++i) {
      int h = __hip_atomic_load(&hist[i], __ATOMIC_RELAXED, __HIP_MEMORY_SCOPE_AGENT);
      levelStart[i] = acc;
      acc += h;
    }
    levelStart[nL] = acc;   // == NG
  }
  __syncthreads();
  for (int g = tid; g < NG; g += 1024) {
    int l = level[g];
    int off = atomicAdd(&cursor[l], 1);
    levelList[levelStart[l] + off] = g;
  }
}

__device__ __forceinline__ void atomic_store_f(float* p, float v) {
  __hip_atomic_store(p, v, __ATOMIC_RELAXED, __HIP_MEMORY_SCOPE_AGENT);
}
__device__ __forceinline__ void atomic_store_f2(float* p, float x, float y) {
  float2 v = make_float2(x, y);
  unsigned long long u;
  __builtin_memcpy(&u, &v, 8);
  __hip_atomic_store((unsigned long long*)p, u, __ATOMIC_RELAXED, __HIP_MEMORY_SCOPE_AGENT);
}

__device__ __forceinline__ void grid_bar(int* ctr, int& barNum) {
  ++barNum;
  __syncthreads();                 // all waves' work + stores drained
  if (threadIdx.x == 0) {
    __hip_atomic_fetch_add(ctr, 1, __ATOMIC_ACQ_REL, __HIP_MEMORY_SCOPE_AGENT);
    const int need = NB * barNum;
    while (__hip_atomic_load(ctr, __ATOMIC_ACQUIRE, __HIP_MEMORY_SCOPE_AGENT) < need)
      __builtin_amdgcn_s_sleep(2);
  }
  __syncthreads();
}

__global__ __launch_bounds__(BLK, 2)
void game_levels_kernel(const float* __restrict__ Wp,   const float* __restrict__ bp,
                        const float* __restrict__ W_ih, const float* __restrict__ b_ih,
                        const float* __restrict__ W_hh, const float* __restrict__ b_hh,
                        const float* __restrict__ ln_g, const float* __restrict__ ln_b,
                        const float* __restrict__ Wi1,  const float* __restrict__ bi1,
                        const float* __restrict__ Wi2,  const float* __restrict__ bi2,
                        const float* __restrict__ fA,   const float* __restrict__ fB,
                        const int* __restrict__ team_a, const int* __restrict__ team_b,
                        const int* __restrict__ a_won,
                        float* __restrict__ emb, float* __restrict__ ctx,
                        const int* __restrict__ levelStart, const int* __restrict__ levelList,
                        const int* __restrict__ nLevels,
                        float* __restrict__ nhbuf, float* __restrict__ hidbuf,
                        int* __restrict__ ctr, int Wcap) {
  const int b    = blockIdx.x;
  const int tid  = threadIdx.x;
  const int lane = tid & 63;
  const int wave = tid >> 6;
  const int d0   = 2 * b;          // owned dims {d0, d0+1}
  const int r_b  = b >> 7;         // hidden row owned
  const int h_b  = b & 127;        // hidden dim owned

  __shared__ float wp[NCIN * 2];       // [e][dim]
  __shared__ float wih[3 * ND * 2];    // [gate][e][dim]
  __shared__ float whh[3 * ND * 2];
  __shared__ float wi1[ND];
  __shared__ float sImp[2];
  __shared__ float sRed[4][8];
  __shared__ float sStat[4];

  // ---- load weight slices into LDS (once) ----
  for (int e = tid; e < NCIN; e += BLK) {
    wp[e * 2 + 0] = Wp[(size_t)d0 * NCIN + e];
    wp[e * 2 + 1] = Wp[(size_t)(d0 + 1) * NCIN + e];
  }
  {
    const int e = tid;  // BLK == ND
#pragma unroll
    for (int gt = 0; gt < 3; ++gt) {
      wih[gt * 1024 + e * 2 + 0] = W_ih[((size_t)gt * ND + d0) * ND + e];
      wih[gt * 1024 + e * 2 + 1] = W_ih[((size_t)gt * ND + d0 + 1) * ND + e];
      whh[gt * 1024 + e * 2 + 0] = W_hh[((size_t)gt * ND + d0) * ND + e];
      whh[gt * 1024 + e * 2 + 1] = W_hh[((size_t)gt * ND + d0 + 1) * ND + e];
    }
    wi1[e] = Wi1[(size_t)h_b * ND + e];
  }
  const float bp0 = bp[d0], bp1 = bp[d0 + 1];
  float bihv[3][2], bhhv[3][2];
#pragma unroll
  for (int gt = 0; gt < 3; ++gt) {
    bihv[gt][0] = b_ih[gt * ND + d0];     bihv[gt][1] = b_ih[gt * ND + d0 + 1];
    bhhv[gt][0] = b_hh[gt * ND + d0];     bhhv[gt][1] = b_hh[gt * ND + d0 + 1];
  }
  const float bi1h = bi1[h_b];
  const float bi2v = bi2[0];
  __syncthreads();

  const int nL = nLevels[0];
  int barNum = 0;

  for (int L = 0; L < nL; ++L) {
    const int s = levelStart[L], e_ = levelStart[L + 1];
    for (int cs = s; cs < e_; cs += Wcap) {
      const int W = min(e_ - cs, Wcap);

      // ================= phase A: proj slices -> ctx =================
      for (int t = wave; t < 2 * W; t += 8) {
        const int w = t >> 1, row = t & 1;
        const int g = levelList[cs + w];
        const int ta = team_a[g], tb = team_b[g];
        const float aw = (float)a_won[g];
        const float* eS = emb + (size_t)(row ? tb : ta) * ND;
        const float* eO = emb + (size_t)(row ? ta : tb) * ND;
        const float* fp = (row ? fB : fA) + (size_t)g * NF;
        const float wonv = row ? 1.0f - aw : aw;
        float a0 = 0.f, a1 = 0.f;
#pragma unroll
        for (int k = 0; k < 17; ++k) {
          const int e = k * 64 + lane;
          float cv;
          if (e < ND)            cv = eS[e];
          else if (e < 2 * ND)   cv = eO[e - ND];
          else if (e < 2 * ND + NF) cv = fp[e - 2 * ND];
          else if (e == NCIN - 1) cv = wonv;
          else                   cv = 0.f;
          const int ec = (e < NCIN) ? e : (NCIN - 1);
          const float2 wv = *(const float2*)&wp[ec * 2];
          a0 = fmaf(cv, wv.x, a0);
          a1 = fmaf(cv, wv.y, a1);
        }
#pragma unroll
        for (int off = 32; off > 0; off >>= 1) {
          a0 += __shfl_xor(a0, off);
          a1 += __shfl_xor(a1, off);
        }
        if (lane == 0) {
          const float p0 = fmaxf(a0 + bp0, 0.f);
          const float p1 = fmaxf(a1 + bp1, 0.f);
          atomic_store_f2(ctx + (size_t)g * 1024 + row * ND + d0, p0, p1);
        }
      }
      grid_bar(ctr, barNum);

      // ============ phase C: gate slices -> new_h; B1: hidden ============
      for (int t = wave; t < 2 * W; t += 8) {
        const int w = t >> 1, row = t & 1;
        const int g = levelList[cs + w];
        const int team = row ? team_b[g] : team_a[g];
        const float* projp = ctx + (size_t)g * 1024 + row * ND;
        const float* ep    = emb + (size_t)team * ND;
        float ai[3][2] = {{0.f,0.f},{0.f,0.f},{0.f,0.f}};
        float ah[3][2] = {{0.f,0.f},{0.f,0.f},{0.f,0.f}};
#pragma unroll
        for (int k = 0; k < 8; ++k) {
          const int e = k * 64 + lane;
          const float pv = projp[e];
          const float ev = ep[e];
#pragma unroll
          for (int gt = 0; gt < 3; ++gt) {
            const float2 wi = *(const float2*)&wih[gt * 1024 + e * 2];
            const float2 wh = *(const float2*)&whh[gt * 1024 + e * 2];
            ai[gt][0] = fmaf(pv, wi.x, ai[gt][0]);
            ai[gt][1] = fmaf(pv, wi.y, ai[gt][1]);
            ah[gt][0] = fmaf(ev, wh.x, ah[gt][0]);
            ah[gt][1] = fmaf(ev, wh.y, ah[gt][1]);
          }
        }
#pragma unroll
        for (int gt = 0; gt < 3; ++gt)
#pragma unroll
          for (int d = 0; d < 2; ++d) {
#pragma unroll
            for (int off = 32; off > 0; off >>= 1) {
              ai[gt][d] += __shfl_xor(ai[gt][d], off);
              ah[gt][d] += __shfl_xor(ah[gt][d], off);
            }
          }
        if (lane == 0) {
          float nhv[2];
#pragma unroll
          for (int d = 0; d < 2; ++d) {
            const float ir = ai[0][d] + bihv[0][d], iz = ai[1][d] + bihv[1][d], in_ = ai[2][d] + bihv[2][d];
            const float hr = ah[0][d] + bhhv[0][d], hz = ah[1][d] + bhhv[1][d], hn = ah[2][d] + bhhv[2][d];
            const float r = sigmf(ir + hr);
            const float z = sigmf(iz + hz);
            const float n = tanhf(in_ + r * hn);
            const float ev_d = ep[d0 + d];
            nhv[d] = (1.f - z) * n + z * ev_d;
          }
          atomic_store_f2(nhbuf + (size_t)w * 1024 + row * ND + d0, nhv[0], nhv[1]);
        }
      }
      // B1: hidden[r_b][h_b] per game
      for (int w = wave; w < W; w += 8) {
        const int g = levelList[cs + w];
        const float* projp = ctx + (size_t)g * 1024 + r_b * ND;
        float acc = 0.f;
#pragma unroll
        for (int j = 0; j < 8; ++j) {
          const int e = j * 64 + lane;
          acc = fmaf(projp[e], wi1[e], acc);
        }
#pragma unroll
        for (int off = 32; off > 0; off >>= 1) acc += __shfl_xor(acc, off);
        if (lane == 0)
          atomic_store_f(hidbuf + (size_t)w * 256 + r_b * NH + h_b, fmaxf(acc + bi1h, 0.f));
      }
      grid_bar(ctr, barNum);

      // ======= phase D (owner blocks): imp, blend, layernorm, write =======
      for (int w = b; w < W; w += NB) {
        const int g = levelList[cs + w];
        const int ta = team_a[g], tb = team_b[g];
        if (wave < 2) {
          const float* hp = hidbuf + (size_t)w * 256 + wave * NH;
          float acc = fmaf(hp[lane], Wi2[lane], 0.f);
          acc = fmaf(hp[64 + lane], Wi2[64 + lane], acc);
#pragma unroll
          for (int off = 32; off > 0; off >>= 1) acc += __shfl_xor(acc, off);
          if (lane == 0) sImp[wave] = sigmf(acc + bi2v);
        }
        __syncthreads();
        const float imp0 = sImp[0], imp1 = sImp[1];
        const float e0 = emb[(size_t)ta * ND + tid];
        const float e1 = emb[(size_t)tb * ND + tid];
        const float nh0 = nhbuf[(size_t)w * 1024 + tid];
        const float nh1 = nhbuf[(size_t)w * 1024 + ND + tid];
        const float u0 = e0 + imp0 * (nh0 - e0);
        const float u1 = e1 + imp1 * (nh1 - e1);

        float s0 = u0, q0 = u0 * u0, s1 = u1, q1 = u1 * u1;
#pragma unroll
        for (int off = 32; off > 0; off >>= 1) {
          s0 += __shfl_xor(s0, off); q0 += __shfl_xor(q0, off);
          s1 += __shfl_xor(s1, off); q1 += __shfl_xor(q1, off);
        }
        if (lane == 0) { sRed[0][wave] = s0; sRed[1][wave] = q0; sRed[2][wave] = s1; sRed[3][wave] = q1; }
        __syncthreads();
        if (tid == 0) {
          float S0 = 0, Q0 = 0, S1 = 0, Q1 = 0;
#pragma unroll
          for (int v = 0; v < 8; ++v) { S0 += sRed[0][v]; Q0 += sRed[1][v]; S1 += sRed[2][v]; Q1 += sRed[3][v]; }
          const float mu0 = S0 * (1.0f / ND), mu1 = S1 * (1.0f / ND);
          const float v0 = Q0 * (1.0f / ND) - mu0 * mu0;
          const float v1 = Q1 * (1.0f / ND) - mu1 * mu1;
          sStat[0] = mu0; sStat[1] = 1.0f / sqrtf(v0 + 1e-5f);
          sStat[2] = mu1; sStat[3] = 1.0f / sqrtf(v1 + 1e-5f);
        }
        __syncthreads();
        const float gg = ln_g[tid], bb = ln_b[tid];
        const float o0 = (u0 - sStat[0]) * sStat[1] * gg + bb;
        const float o1 = (u1 - sStat[2]) * sStat[3] * gg + bb;
        if (ta != tb) emb[(size_t)ta * ND + tid] = o0;
        emb[(size_t)tb * ND + tid] = o1;
        __syncthreads();   // sImp/sRed reuse next game
      }
      grid_bar(ctr, barNum);
    }
  }
}

extern "C" void kernel_launch(void* const* d_in, const int* in_sizes, int n_in,
                              void* d_out, int out_size, void* d_ws, size_t ws_size,
                              hipStream_t stream) {
  const float* emb_table = (const float*)d_in[0];
  const float* Wp    = (const float*)d_in[1];
  const float* bp    = (const float*)d_in[2];
  const float* W_ih  = (const float*)d_in[3];
  const float* b_ih  = (const float*)d_in[4];
  const float* W_hh  = (const float*)d_in[5];
  const float* b_hh  = (const float*)d_in[6];
  const float* ln_g  = (const float*)d_in[7];
  const float* ln_b  = (const float*)d_in[8];
  const float* Wi1   = (const float*)d_in[9];
  const float* bi1   = (const float*)d_in[10];
  const float* Wi2   = (const float*)d_in[11];
  const float* bi2   = (const float*)d_in[12];
  const float* fA    = (const float*)d_in[13];
  const float* fB    = (const float*)d_in[14];
  const int*   team_a = (const int*)d_in[15];
  const int*   team_b = (const int*)d_in[16];
  const int*   a_won  = (const int*)d_in[17];

  float* out = (float*)d_out;
  float* emb = out;
  float* ctx = out + (size_t)NT * ND;

  // ---- workspace layout (ints) ----
  int* ip         = (int*)d_ws;
  int* ctr        = ip;             // [0..15]
  int* nLevels    = ip + 16;        // [16..31]
  int* dep0       = ip + 32;
  int* dep1       = dep0 + NG;
  int* level      = dep1 + NG;
  int* hist       = level + NG;
  int* cursor     = hist + NG;
  int* levelStart = cursor + NG;        // NG+2 ints
  int* levelList  = levelStart + NG + 2;
  size_t control = (size_t)((char*)(levelList + NG) - (char*)d_ws);
  control = (control + 255) & ~(size_t)255;

  int Wcap = 1024;
  if (ws_size > control + 4096) {
    size_t avail = (ws_size - control) / ((size_t)(1024 + 256) * sizeof(float));
    if (avail < (size_t)Wcap) Wcap = (int)avail;
  } else {
    Wcap = 8;
  }
  if (Wcap < 8) Wcap = 8;
  float* nhbuf  = (float*)((char*)d_ws + control);
  float* hidbuf = nhbuf + (size_t)Wcap * 1024;

  hipMemcpyAsync(emb, emb_table, (size_t)NT * ND * sizeof(float),
                 hipMemcpyDeviceToDevice, stream);
  zero_kernel<<<1, 64, 0, stream>>>(ctr, 32);
  deps_kernel<<<(NG + 255) / 256, 256, 0, stream>>>(team_a, team_b, dep0, dep1);
  levels_kernel<<<1, 1024, 0, stream>>>(dep0, dep1, level, nLevels);
  sort_kernel<<<1, 1024, 0, stream>>>(level, nLevels, hist, cursor, levelStart, levelList);
  game_levels_kernel<<<NB, BLK, 0, stream>>>(
      Wp, bp, W_ih, b_ih, W_hh, b_hh, ln_g, ln_b, Wi1, bi1, Wi2, bi2,
      fA, fB, team_a, team_b, a_won, emb, ctx,
      levelStart, levelList, nLevels, nhbuf, hidbuf, ctr, Wcap);
}

// Round 3
// 38968.860 us; speedup vs baseline: 21.8637x; 1.7435x over previous
//
#include <hip/hip_runtime.h>
#include <math.h>

// ---------------------------------------------------------------------------
// GameProcessor round 3: level-synchronous, weight-stationary dataflow with a
// distributed sense-epoch grid barrier (round-2's single-counter fetch_add
// barrier cost ~25us/barrier from 256 serialized cross-XCD RMWs on one line).
//
//  * 256 blocks x 1024 threads (1 block/CU). Block b owns output dims
//    {2b,2b+1}; weight slices live in LDS (~35 KB) for the whole kernel.
//  * per level: phase A (proj -> ctx) | bar | phase C (gates -> new_h) +
//    B1 (hidden) | bar | phase D (imp, blend, layernorm, emb write) | bar.
//  * barrier: per-block arrival flag on its own 128B line (release store);
//    block 0 polls all flags in parallel (one lane per block), then
//    release-stores a go-epoch everyone spins on (relaxed poll + acquire
//    fence). Epochs zeroed every launch (graph replays reuse d_ws).
//  * phase A: row0 in lanes 0-31, row1 in lanes 32-63 (LDS weight broadcast).
//  * phase C: ih-dot in lanes 0-31 (proj input), hh-dot in lanes 32-63 (emb
//    input); cross results with one xor-32 shuffle set.
// ---------------------------------------------------------------------------

#define NG   30000
#define NT   364
#define ND   512
#define NF   28
#define NH   128
#define NCIN 1053
#define NB   256
#define BLK  1024

__device__ __forceinline__ float sigmf(float x) { return 1.0f / (1.0f + expf(-x)); }

__global__ void zero_kernel(int* p, int n) {
  int i = blockIdx.x * blockDim.x + threadIdx.x;
  if (i < n) p[i] = 0;
}

// dep0[g]/dep1[g] = most recent earlier game touching team_a[g]/team_b[g], or -1.
__global__ void deps_kernel(const int* __restrict__ ta, const int* __restrict__ tb,
                            int* __restrict__ dep0, int* __restrict__ dep1) {
  int g = blockIdx.x * blockDim.x + threadIdx.x;
  if (g >= NG) return;
  int a = ta[g], b = tb[g];
  int d0 = -1, d1 = -1;
  for (int p = g - 1; p >= 0; --p) {
    int pa = ta[p], pb = tb[p];
    if (d0 < 0 && (pa == a || pb == a)) d0 = p;
    if (d1 < 0 && (pa == b || pb == b)) d1 = p;
    if (d0 >= 0 && d1 >= 0) break;
  }
  dep0[g] = d0;
  dep1[g] = d1;
}

// Exact DAG levels via chunked monotone relaxation. Single block, 1024 thr.
__global__ void levels_kernel(const int* __restrict__ d0a, const int* __restrict__ d1a,
                              int* __restrict__ level, int* __restrict__ nLevels) {
  __shared__ int lv[1024];
  __shared__ int changed;
  __shared__ int smax;
  const int tid = threadIdx.x;
  int localMax = 0;
  if (tid == 0) smax = 0;
  for (int base = 0; base < NG; base += 1024) {
    const int g = base + tid;
    const bool val = g < NG;
    int ic0 = -1, ic1 = -1, b = 0;
    if (val) {
      int d0 = d0a[g], d1 = d1a[g];
      if (d0 >= 0) { if (d0 < base) b = max(b, level[d0] + 1); else ic0 = d0 - base; }
      if (d1 >= 0) { if (d1 < base) b = max(b, level[d1] + 1); else ic1 = d1 - base; }
    }
    lv[tid] = b;
    __syncthreads();
    for (;;) {
      if (tid == 0) changed = 0;
      __syncthreads();
      int nl = lv[tid];
      if (ic0 >= 0) nl = max(nl, lv[ic0] + 1);
      if (ic1 >= 0) nl = max(nl, lv[ic1] + 1);
      if (val && nl != lv[tid]) { lv[tid] = nl; changed = 1; }
      __syncthreads();
      if (!changed) break;
    }
    if (val) { level[g] = lv[tid]; localMax = max(localMax, lv[tid]); }
    __syncthreads();
  }
  atomicMax(&smax, localMax);
  __syncthreads();
  if (tid == 0) nLevels[0] = smax + 1;
}

// Counting sort by level. Single block, 1024 threads.
__global__ void sort_kernel(const int* __restrict__ level, const int* __restrict__ nLevels,
                            int* __restrict__ hist, int* __restrict__ cursor,
                            int* __restrict__ levelStart, int* __restrict__ levelList) {
  const int tid = threadIdx.x;
  const int nL = nLevels[0];
  for (int i = tid; i < NG; i += 1024) { hist[i] = 0; cursor[i] = 0; }
  __syncthreads();
  for (int g = tid; g < NG; g += 1024) atomicAdd(&hist[level[g]], 1);
  __syncthreads();
  if (tid == 0) {
    int acc = 0;
    for (int i = 0; i < nL; ++i) {
      int h = hist[i];
      levelStart[i] = acc;
      acc += h;
    }
    levelStart[nL] = acc;
  }
  __syncthreads();
  for (int g = tid; g < NG; g += 1024) {
    int l = level[g];
    int off = atomicAdd(&cursor[l], 1);
    levelList[levelStart[l] + off] = g;
  }
}

__device__ __forceinline__ void atomic_store_f(float* p, float v) {
  __hip_atomic_store(p, v, __ATOMIC_RELAXED, __HIP_MEMORY_SCOPE_AGENT);
}
__device__ __forceinline__ void atomic_store_f2(float* p, float x, float y) {
  float2 v = make_float2(x, y);
  unsigned long long u;
  __builtin_memcpy(&u, &v, 8);
  __hip_atomic_store((unsigned long long*)p, u, __ATOMIC_RELAXED, __HIP_MEMORY_SCOPE_AGENT);
}

// Distributed sense-epoch grid barrier. arr[b*32] on its own 128B line.
__device__ __forceinline__ void grid_bar(int* go, int* arr, int& epoch) {
  ++epoch;
  __syncthreads();
  if (blockIdx.x == 0) {
    const int t = threadIdx.x;
    if (t >= 1 && t < NB) {
      while (__hip_atomic_load(arr + t * 32, __ATOMIC_RELAXED, __HIP_MEMORY_SCOPE_AGENT) < epoch)
        __builtin_amdgcn_s_sleep(1);
    }
    __builtin_amdgcn_fence(__ATOMIC_ACQUIRE, "agent");
    __syncthreads();
    if (t == 0)
      __hip_atomic_store(go, epoch, __ATOMIC_RELEASE, __HIP_MEMORY_SCOPE_AGENT);
  } else {
    if (threadIdx.x == 0) {
      __hip_atomic_store(arr + blockIdx.x * 32, epoch, __ATOMIC_RELEASE, __HIP_MEMORY_SCOPE_AGENT);
      while (__hip_atomic_load(go, __ATOMIC_RELAXED, __HIP_MEMORY_SCOPE_AGENT) < epoch)
        __builtin_amdgcn_s_sleep(1);
      __builtin_amdgcn_fence(__ATOMIC_ACQUIRE, "agent");
    }
    __syncthreads();
  }
}

__global__ __launch_bounds__(BLK, 1)
void game_levels_kernel(const float* __restrict__ Wp,   const float* __restrict__ bp,
                        const float* __restrict__ W_ih, const float* __restrict__ b_ih,
                        const float* __restrict__ W_hh, const float* __restrict__ b_hh,
                        const float* __restrict__ ln_g, const float* __restrict__ ln_b,
                        const float* __restrict__ Wi1,  const float* __restrict__ bi1,
                        const float* __restrict__ Wi2,  const float* __restrict__ bi2,
                        const float* __restrict__ fA,   const float* __restrict__ fB,
                        const int* __restrict__ team_a, const int* __restrict__ team_b,
                        const int* __restrict__ a_won,
                        float* __restrict__ emb, float* __restrict__ ctx,
                        const int* __restrict__ levelStart, const int* __restrict__ levelList,
                        const int* __restrict__ nLevels,
                        float* __restrict__ nhbuf, float* __restrict__ hidbuf,
                        int* __restrict__ go, int* __restrict__ arr, int Wcap) {
  const int b    = blockIdx.x;
  const int tid  = threadIdx.x;
  const int lane = tid & 63;
  const int wave = tid >> 6;
  const int half = lane >> 5;      // 0: lanes 0-31, 1: lanes 32-63
  const int l5   = lane & 31;
  const int d0   = 2 * b;          // owned dims {d0, d0+1}
  const int r_b  = b >> 7;         // hidden row owned
  const int h_b  = b & 127;        // hidden dim owned

  __shared__ float wp[NCIN * 2];       // float2 per input elem
  __shared__ float wih[3 * ND * 2];    // [gate][e] float2
  __shared__ float whh[3 * ND * 2];
  __shared__ float wi1[ND];
  __shared__ float sImp[2];
  __shared__ float sRed[4][8];
  __shared__ float sStat[4];

  const float2* wp2  = (const float2*)wp;
  const float2* wih2 = (const float2*)wih;
  const float2* whh2 = (const float2*)whh;

  // ---- load weight slices into LDS (once) ----
  for (int e = tid; e < NCIN; e += BLK) {
    wp[e * 2 + 0] = Wp[(size_t)d0 * NCIN + e];
    wp[e * 2 + 1] = Wp[(size_t)(d0 + 1) * NCIN + e];
  }
  for (int e = tid; e < ND; e += BLK) {
#pragma unroll
    for (int gt = 0; gt < 3; ++gt) {
      wih[gt * 1024 + e * 2 + 0] = W_ih[((size_t)gt * ND + d0) * ND + e];
      wih[gt * 1024 + e * 2 + 1] = W_ih[((size_t)gt * ND + d0 + 1) * ND + e];
      whh[gt * 1024 + e * 2 + 0] = W_hh[((size_t)gt * ND + d0) * ND + e];
      whh[gt * 1024 + e * 2 + 1] = W_hh[((size_t)gt * ND + d0 + 1) * ND + e];
    }
    wi1[e] = Wi1[(size_t)h_b * ND + e];
  }
  const float bp0 = bp[d0], bp1 = bp[d0 + 1];
  float bihv[3][2], bhhv[3][2];
#pragma unroll
  for (int gt = 0; gt < 3; ++gt) {
    bihv[gt][0] = b_ih[gt * ND + d0];     bihv[gt][1] = b_ih[gt * ND + d0 + 1];
    bhhv[gt][0] = b_hh[gt * ND + d0];     bhhv[gt][1] = b_hh[gt * ND + d0 + 1];
  }
  const float bi1h = bi1[h_b];
  const float bi2v = bi2[0];
  const float w2a = Wi2[lane], w2b = Wi2[64 + lane];
  const float gg = (tid < ND) ? ln_g[tid] : 0.f;
  const float bb = (tid < ND) ? ln_b[tid] : 0.f;
  __syncthreads();

  const int nL = nLevels[0];
  int epoch = 0;

  for (int L = 0; L < nL; ++L) {
    const int s = levelStart[L], e_ = levelStart[L + 1];
    for (int cs = s; cs < e_; cs += Wcap) {
      const int W = min(e_ - cs, Wcap);

      // ========= phase A: proj -> ctx (row0 lanes 0-31, row1 lanes 32-63) ===
      for (int w = wave; w < W; w += 16) {
        const int g = levelList[cs + w];
        const int ta = team_a[g], tb = team_b[g];
        const float aw = (float)a_won[g];
        const float* eA = emb + (size_t)ta * ND;
        const float* eB = emb + (size_t)tb * ND;
        const float* fp = (half ? fB : fA) + (size_t)g * NF;
        float a0 = 0.f, a1 = 0.f;
#pragma unroll
        for (int k = 0; k < 16; ++k) {
          const int e = k * 32 + l5;
          const float va = eA[e], vb = eB[e];
          const float2 w1 = wp2[e];
          const float2 w2 = wp2[ND + e];
          const float cs1 = half ? vb : va;   // e_self
          const float cs2 = half ? va : vb;   // e_opp
          a0 = fmaf(cs1, w1.x, fmaf(cs2, w2.x, a0));
          a1 = fmaf(cs1, w1.y, fmaf(cs2, w2.y, a1));
        }
        if (l5 < NF + 1) {
          const float cv = (l5 < NF) ? fp[l5] : (half ? 1.0f - aw : aw);
          const float2 wv = wp2[2 * ND + l5];
          a0 = fmaf(cv, wv.x, a0);
          a1 = fmaf(cv, wv.y, a1);
        }
#pragma unroll
        for (int off = 16; off > 0; off >>= 1) {
          a0 += __shfl_xor(a0, off);
          a1 += __shfl_xor(a1, off);
        }
        if (l5 == 0) {
          atomic_store_f2(ctx + (size_t)g * 1024 + half * ND + d0,
                          fmaxf(a0 + bp0, 0.f), fmaxf(a1 + bp1, 0.f));
        }
      }
      grid_bar(go, arr, epoch);

      // ==== phase C: gates -> new_h (ih lanes 0-31, hh lanes 32-63); B1 ====
      for (int t = wave; t < 2 * W; t += 16) {
        const int w = t >> 1, row = t & 1;
        const int g = levelList[cs + w];
        const int team = row ? team_b[g] : team_a[g];
        const float* ep = emb + (size_t)team * ND;
        const float* src = half ? ep : (ctx + (size_t)g * 1024 + row * ND);
        const float2* wb = half ? whh2 : wih2;
        float2 ac0 = make_float2(0.f, 0.f), ac1 = ac0, ac2 = ac0;
#pragma unroll
        for (int k = 0; k < 16; ++k) {
          const int e = k * 32 + l5;
          const float v = src[e];
          const float2 q0 = wb[e];
          const float2 q1 = wb[ND + e];
          const float2 q2 = wb[2 * ND + e];
          ac0.x = fmaf(v, q0.x, ac0.x); ac0.y = fmaf(v, q0.y, ac0.y);
          ac1.x = fmaf(v, q1.x, ac1.x); ac1.y = fmaf(v, q1.y, ac1.y);
          ac2.x = fmaf(v, q2.x, ac2.x); ac2.y = fmaf(v, q2.y, ac2.y);
        }
#pragma unroll
        for (int off = 16; off > 0; off >>= 1) {
          ac0.x += __shfl_xor(ac0.x, off); ac0.y += __shfl_xor(ac0.y, off);
          ac1.x += __shfl_xor(ac1.x, off); ac1.y += __shfl_xor(ac1.y, off);
          ac2.x += __shfl_xor(ac2.x, off); ac2.y += __shfl_xor(ac2.y, off);
        }
        // lane0: ih sums; lane32: hh sums. Cross halves.
        const float hx0 = __shfl_xor(ac0.x, 32), hy0 = __shfl_xor(ac0.y, 32);
        const float hx1 = __shfl_xor(ac1.x, 32), hy1 = __shfl_xor(ac1.y, 32);
        const float hx2 = __shfl_xor(ac2.x, 32), hy2 = __shfl_xor(ac2.y, 32);
        if (lane == 0) {
          const float ir0 = ac0.x + bihv[0][0], iz0 = ac1.x + bihv[1][0], in0 = ac2.x + bihv[2][0];
          const float hr0 = hx0 + bhhv[0][0],   hz0 = hx1 + bhhv[1][0],   hn0 = hx2 + bhhv[2][0];
          const float ir1 = ac0.y + bihv[0][1], iz1 = ac1.y + bihv[1][1], in1 = ac2.y + bihv[2][1];
          const float hr1 = hy0 + bhhv[0][1],   hz1 = hy1 + bhhv[1][1],   hn1 = hy2 + bhhv[2][1];
          const float r0 = sigmf(ir0 + hr0), z0 = sigmf(iz0 + hz0);
          const float n0 = tanhf(in0 + r0 * hn0);
          const float r1 = sigmf(ir1 + hr1), z1 = sigmf(iz1 + hz1);
          const float n1 = tanhf(in1 + r1 * hn1);
          const float e0 = ep[d0], e1 = ep[d0 + 1];
          atomic_store_f2(nhbuf + (size_t)w * 1024 + row * ND + d0,
                          (1.f - z0) * n0 + z0 * e0,
                          (1.f - z1) * n1 + z1 * e1);
        }
      }
      // B1: hidden[r_b][h_b] per game
      for (int w = wave; w < W; w += 16) {
        const int g = levelList[cs + w];
        const float* projp = ctx + (size_t)g * 1024 + r_b * ND;
        float acc = 0.f;
#pragma unroll
        for (int j = 0; j < 8; ++j) {
          const int e = j * 64 + lane;
          acc = fmaf(projp[e], wi1[e], acc);
        }
#pragma unroll
        for (int off = 32; off > 0; off >>= 1) acc += __shfl_xor(acc, off);
        if (lane == 0)
          atomic_store_f(hidbuf + (size_t)w * 256 + r_b * NH + h_b, fmaxf(acc + bi1h, 0.f));
      }
      grid_bar(go, arr, epoch);

      // ======= phase D (owner blocks): imp, blend, layernorm, write =======
      for (int w = b; w < W; w += NB) {
        const int g = levelList[cs + w];
        const int ta = team_a[g], tb = team_b[g];
        if (wave < 2) {
          const float* hp = hidbuf + (size_t)w * 256 + wave * NH;
          float acc = fmaf(hp[lane], w2a, 0.f);
          acc = fmaf(hp[64 + lane], w2b, acc);
#pragma unroll
          for (int off = 32; off > 0; off >>= 1) acc += __shfl_xor(acc, off);
          if (lane == 0) sImp[wave] = sigmf(acc + bi2v);
        }
        __syncthreads();
        float u0 = 0.f, u1 = 0.f;
        if (tid < ND) {
          const float imp0 = sImp[0], imp1 = sImp[1];
          const float e0 = emb[(size_t)ta * ND + tid];
          const float e1 = emb[(size_t)tb * ND + tid];
          const float nh0 = nhbuf[(size_t)w * 1024 + tid];
          const float nh1 = nhbuf[(size_t)w * 1024 + ND + tid];
          u0 = e0 + imp0 * (nh0 - e0);
          u1 = e1 + imp1 * (nh1 - e1);
          float s0 = u0, q0 = u0 * u0, s1 = u1, q1 = u1 * u1;
#pragma unroll
          for (int off = 32; off > 0; off >>= 1) {
            s0 += __shfl_xor(s0, off); q0 += __shfl_xor(q0, off);
            s1 += __shfl_xor(s1, off); q1 += __shfl_xor(q1, off);
          }
          if (lane == 0) { sRed[0][wave] = s0; sRed[1][wave] = q0; sRed[2][wave] = s1; sRed[3][wave] = q1; }
        }
        __syncthreads();
        if (tid == 0) {
          float S0 = 0, Q0 = 0, S1 = 0, Q1 = 0;
#pragma unroll
          for (int v = 0; v < 8; ++v) { S0 += sRed[0][v]; Q0 += sRed[1][v]; S1 += sRed[2][v]; Q1 += sRed[3][v]; }
          const float mu0 = S0 * (1.0f / ND), mu1 = S1 * (1.0f / ND);
          const float v0 = Q0 * (1.0f / ND) - mu0 * mu0;
          const float v1 = Q1 * (1.0f / ND) - mu1 * mu1;
          sStat[0] = mu0; sStat[1] = 1.0f / sqrtf(v0 + 1e-5f);
          sStat[2] = mu1; sStat[3] = 1.0f / sqrtf(v1 + 1e-5f);
        }
        __syncthreads();
        if (tid < ND) {
          const float o0 = (u0 - sStat[0]) * sStat[1] * gg + bb;
          const float o1 = (u1 - sStat[2]) * sStat[3] * gg + bb;
          if (ta != tb) emb[(size_t)ta * ND + tid] = o0;
          emb[(size_t)tb * ND + tid] = o1;
        }
        __syncthreads();
      }
      grid_bar(go, arr, epoch);
    }
  }
}

extern "C" void kernel_launch(void* const* d_in, const int* in_sizes, int n_in,
                              void* d_out, int out_size, void* d_ws, size_t ws_size,
                              hipStream_t stream) {
  const float* emb_table = (const float*)d_in[0];
  const float* Wp    = (const float*)d_in[1];
  const float* bp    = (const float*)d_in[2];
  const float* W_ih  = (const float*)d_in[3];
  const float* b_ih  = (const float*)d_in[4];
  const float* W_hh  = (const float*)d_in[5];
  const float* b_hh  = (const float*)d_in[6];
  const float* ln_g  = (const float*)d_in[7];
  const float* ln_b  = (const float*)d_in[8];
  const float* Wi1   = (const float*)d_in[9];
  const float* bi1   = (const float*)d_in[10];
  const float* Wi2   = (const float*)d_in[11];
  const float* bi2   = (const float*)d_in[12];
  const float* fA    = (const float*)d_in[13];
  const float* fB    = (const float*)d_in[14];
  const int*   team_a = (const int*)d_in[15];
  const int*   team_b = (const int*)d_in[16];
  const int*   a_won  = (const int*)d_in[17];

  float* out = (float*)d_out;
  float* emb = out;
  float* ctx = out + (size_t)NT * ND;

  // ---- workspace layout (ints) ----
  int* ip         = (int*)d_ws;
  int* go         = ip;                 // line 0
  int* arr        = ip + 32;            // NB lines, 128B apart
  int* nLevels    = ip + 32 + NB * 32;  // one line
  int* dep0       = nLevels + 32;
  int* dep1       = dep0 + NG;
  int* level      = dep1 + NG;
  int* hist       = level + NG;
  int* cursor     = hist + NG;
  int* levelStart = cursor + NG;        // NG+2 ints
  int* levelList  = levelStart + NG + 2;
  const int flagInts = 32 + NB * 32;    // go + arr (zeroed each launch)
  size_t control = (size_t)((char*)(levelList + NG) - (char*)d_ws);
  control = (control + 255) & ~(size_t)255;

  int Wcap = 1024;
  if (ws_size > control + 4096) {
    size_t avail = (ws_size - control) / ((size_t)(1024 + 256) * sizeof(float));
    if (avail < (size_t)Wcap) Wcap = (int)avail;
  } else {
    Wcap = 8;
  }
  if (Wcap < 8) Wcap = 8;
  float* nhbuf  = (float*)((char*)d_ws + control);
  float* hidbuf = nhbuf + (size_t)Wcap * 1024;

  hipMemcpyAsync(emb, emb_table, (size_t)NT * ND * sizeof(float),
                 hipMemcpyDeviceToDevice, stream);
  zero_kernel<<<(flagInts + 255) / 256, 256, 0, stream>>>(ip, flagInts);
  deps_kernel<<<(NG + 255) / 256, 256, 0, stream>>>(team_a, team_b, dep0, dep1);
  levels_kernel<<<1, 1024, 0, stream>>>(dep0, dep1, level, nLevels);
  sort_kernel<<<1, 1024, 0, stream>>>(level, nLevels, hist, cursor, levelStart, levelList);
  game_levels_kernel<<<NB, BLK, 0, stream>>>(
      Wp, bp, W_ih, b_ih, W_hh, b_hh, ln_g, ln_b, Wi1, bi1, Wi2, bi2,
      fA, fB, team_a, team_b, a_won, emb, ctx,
      levelStart, levelList, nLevels, nhbuf, hidbuf, go, arr, Wcap);
}